// Round 8
// baseline (72.136 us; speedup 1.0000x reference)
//
#include <hip/hip_runtime.h>

// Bahdanau additive attention, f32, 3 kernels.
// B=8, TQ=128, TK=512, NIN=512, H=128, NV=512.
// out = [context (B*TQ*NV), attn (B*TQ*TK)] f32.

#define B_    8
#define TQ_   128
#define TK_   512
#define NIN_  512
#define H_    128
#define NV_   512
#define NQR   (B_*TQ_)           // 1024 query rows
#define NROWS (NQR + B_*TK_)     // 5120 projected rows

#define C2_   2.8853900817779268f   // 2*log2(e)
#define L2E_  1.4426950408889634f

__device__ __forceinline__ float fexp2(float x){ return __builtin_amdgcn_exp2f(x); }
__device__ __forceinline__ float frcp (float x){ return __builtin_amdgcn_rcpf(x); }

// ---------------------------------------------------------------- proj ----
// out[row][h] = (A[row,:] . W[h,:] + bias[h]) * C2   (pre-scaled for scores)
// 128 thr, tile 16 rows x 64 h (h-slab), full K=512, 2x4 microtile,
// reg-prefetch. grid 640 = (NROWS/16) x 2 slabs = 2.5 blocks/CU.
__global__ __launch_bounds__(128, 4) void proj_kernel(
        const float* __restrict__ query, const float* __restrict__ keys,
        const float* __restrict__ Wq, const float* __restrict__ bq,
        const float* __restrict__ Wk, const float* __restrict__ bk,
        float* __restrict__ qp, float* __restrict__ kp) {
    __shared__ float at[32][20];     // [kk][row], 16 rows
    __shared__ float wt[32][68];     // [kk][h],  64 h
    const int tid = threadIdx.x;
    const int r0  = (blockIdx.x >> 1) * 16;
    const int h0  = (blockIdx.x & 1) * 64;
    const float* in; const float* W; const float* bias; float* outp;
    if (r0 < NQR) {
        in = query + (size_t)r0 * NIN_; W = Wq; bias = bq;
        outp = qp + (size_t)r0 * H_;
    } else {
        const int rk = r0 - NQR;
        in = keys + (size_t)rk * NIN_;  W = Wk; bias = bk;
        outp = kp + (size_t)rk * H_;
    }

    const int r2  = (tid >> 4) * 2;      // 2 rows (0..14)
    const int h4l = (tid & 15) * 4;      // 4 h within slab (0..60)
    const int sr  = tid >> 3;            // stage row 0..15
    const int skq = (tid & 7) * 4;       // stage k quad

    const float* pA  = in + (size_t)sr * NIN_ + skq;
    const float* pW0 = W + (size_t)(h0 + sr     ) * NIN_ + skq;
    const float* pW1 = W + (size_t)(h0 + sr + 16) * NIN_ + skq;
    const float* pW2 = W + (size_t)(h0 + sr + 32) * NIN_ + skq;
    const float* pW3 = W + (size_t)(h0 + sr + 48) * NIN_ + skq;

    float4 af = *(const float4*)pA;
    float4 w0 = *(const float4*)pW0, w1 = *(const float4*)pW1;
    float4 w2 = *(const float4*)pW2, w3 = *(const float4*)pW3;

    float acc[2][4] = {{0.f,0.f,0.f,0.f},{0.f,0.f,0.f,0.f}};

    for (int c = 0; c < 16; ++c) {
        __syncthreads();
        at[skq+0][sr] = af.x; at[skq+1][sr] = af.y;
        at[skq+2][sr] = af.z; at[skq+3][sr] = af.w;
        wt[skq+0][sr   ] = w0.x; wt[skq+1][sr   ] = w0.y;
        wt[skq+2][sr   ] = w0.z; wt[skq+3][sr   ] = w0.w;
        wt[skq+0][sr+16] = w1.x; wt[skq+1][sr+16] = w1.y;
        wt[skq+2][sr+16] = w1.z; wt[skq+3][sr+16] = w1.w;
        wt[skq+0][sr+32] = w2.x; wt[skq+1][sr+32] = w2.y;
        wt[skq+2][sr+32] = w2.z; wt[skq+3][sr+32] = w2.w;
        wt[skq+0][sr+48] = w3.x; wt[skq+1][sr+48] = w3.y;
        wt[skq+2][sr+48] = w3.z; wt[skq+3][sr+48] = w3.w;
        __syncthreads();
        if (c + 1 < 16) {
            pA += 32; pW0 += 32; pW1 += 32; pW2 += 32; pW3 += 32;
            af = *(const float4*)pA;
            w0 = *(const float4*)pW0; w1 = *(const float4*)pW1;
            w2 = *(const float4*)pW2; w3 = *(const float4*)pW3;
        }
#pragma unroll 8
        for (int kk = 0; kk < 32; ++kk) {
            const float2 a = *(const float2*)&at[kk][r2];
            const float4 w = *(const float4*)&wt[kk][h4l];
            acc[0][0] = fmaf(a.x, w.x, acc[0][0]);
            acc[0][1] = fmaf(a.x, w.y, acc[0][1]);
            acc[0][2] = fmaf(a.x, w.z, acc[0][2]);
            acc[0][3] = fmaf(a.x, w.w, acc[0][3]);
            acc[1][0] = fmaf(a.y, w.x, acc[1][0]);
            acc[1][1] = fmaf(a.y, w.y, acc[1][1]);
            acc[1][2] = fmaf(a.y, w.z, acc[1][2]);
            acc[1][3] = fmaf(a.y, w.w, acc[1][3]);
        }
    }

    const float4 b4 = *(const float4*)&bias[h0 + h4l];
#pragma unroll
    for (int i = 0; i < 2; ++i) {
        float4 o = {(acc[i][0] + b4.x) * C2_, (acc[i][1] + b4.y) * C2_,
                    (acc[i][2] + b4.z) * C2_, (acc[i][3] + b4.w) * C2_};
        *(float4*)&outp[(size_t)(r2 + i) * H_ + h0 + h4l] = o;
    }
}

// -------------------------------------------------------------- scores ----
// Per block: batch b, 2 q rows. qp/kp pre-scaled by C2 (bias included).
// score = bo + sumWo - 2*sum_h Wo_h/(e^(2x_h)+1); softmax over k.
__global__ __launch_bounds__(256, 4) void scores_kernel(
        const float* __restrict__ qp, const float* __restrict__ kp,
        const float* __restrict__ Wo, const float* __restrict__ bo,
        float* __restrict__ out_attn) {
    __shared__ float qs2[2][H_];
    __shared__ float w2[H_];        // -2 * Wo
    __shared__ float sc[2][TK_];

    const int tid = threadIdx.x;
    const int b   = blockIdx.y;
    const int q0  = blockIdx.x * 2;
    const int lane = tid & 63;

    qs2[tid >> 7][tid & 127] =
        qp[(size_t)(b * TQ_ + q0 + (tid >> 7)) * H_ + (tid & 127)];
    if (tid < H_) w2[tid] = Wo[tid] * -2.0f;
    __syncthreads();

    float sw = w2[lane] + w2[lane + 64];
#pragma unroll
    for (int m = 1; m < 64; m <<= 1) sw += __shfl_xor(sw, m);
    const float sbase = bo[0] - 0.5f * sw;

#pragma unroll
    for (int half = 0; half < 2; ++half) {
        const int k = tid + half * 256;
        const float4* kp4 = (const float4*)&kp[(size_t)(b * TK_ + k) * H_];
        float s0 = 0.f, s1 = 0.f;
#pragma unroll 4
        for (int hb = 0; hb < 32; ++hb) {
            const float4 kv  = kp4[hb];
            const float4 wv  = *(const float4*)&w2[hb * 4];
            const float4 q0v = *(const float4*)&qs2[0][hb * 4];
            const float4 q1v = *(const float4*)&qs2[1][hb * 4];
            s0 = fmaf(wv.x, frcp(fexp2(q0v.x + kv.x) + 1.f), s0);
            s0 = fmaf(wv.y, frcp(fexp2(q0v.y + kv.y) + 1.f), s0);
            s0 = fmaf(wv.z, frcp(fexp2(q0v.z + kv.z) + 1.f), s0);
            s0 = fmaf(wv.w, frcp(fexp2(q0v.w + kv.w) + 1.f), s0);
            s1 = fmaf(wv.x, frcp(fexp2(q1v.x + kv.x) + 1.f), s1);
            s1 = fmaf(wv.y, frcp(fexp2(q1v.y + kv.y) + 1.f), s1);
            s1 = fmaf(wv.z, frcp(fexp2(q1v.z + kv.z) + 1.f), s1);
            s1 = fmaf(wv.w, frcp(fexp2(q1v.w + kv.w) + 1.f), s1);
        }
        sc[0][k] = s0 + sbase;
        sc[1][k] = s1 + sbase;
    }
    __syncthreads();

    const int w = tid >> 6;
    if (w < 2) {
        float4 sA = *(const float4*)&sc[w][lane * 8];
        float4 sB = *(const float4*)&sc[w][lane * 8 + 4];
        float m = fmaxf(fmaxf(fmaxf(sA.x, sA.y), fmaxf(sA.z, sA.w)),
                        fmaxf(fmaxf(sB.x, sB.y), fmaxf(sB.z, sB.w)));
#pragma unroll
        for (int mk = 1; mk < 64; mk <<= 1) m = fmaxf(m, __shfl_xor(m, mk));
        float4 eA, eB;
        eA.x = fexp2((sA.x - m) * L2E_); eA.y = fexp2((sA.y - m) * L2E_);
        eA.z = fexp2((sA.z - m) * L2E_); eA.w = fexp2((sA.w - m) * L2E_);
        eB.x = fexp2((sB.x - m) * L2E_); eB.y = fexp2((sB.y - m) * L2E_);
        eB.z = fexp2((sB.z - m) * L2E_); eB.w = fexp2((sB.w - m) * L2E_);
        float s = eA.x + eA.y + eA.z + eA.w + eB.x + eB.y + eB.z + eB.w;
#pragma unroll
        for (int mk = 1; mk < 64; mk <<= 1) s += __shfl_xor(s, mk);
        const float inv = frcp(s);
        eA.x *= inv; eA.y *= inv; eA.z *= inv; eA.w *= inv;
        eB.x *= inv; eB.y *= inv; eB.z *= inv; eB.w *= inv;
        float4* op = (float4*)&out_attn[(size_t)(b * TQ_ + q0 + w) * TK_ + lane * 8];
        op[0] = eA; op[1] = eB;
    }
}

// ------------------------------------------------------------- context ----
// 128 thr, tile 8 q x 64 v, full K=512, 2x2 microtile, reg prefetch.
// grid (128, B) = 1024 blocks = 8 waves/CU.
__global__ __launch_bounds__(128, 4) void context_kernel(
        const float* __restrict__ attn, const float* __restrict__ values,
        float* __restrict__ outc) {
    __shared__ float at[32][12];    // [kk][q], 8 q
    __shared__ float vt[32][68];    // [kk][v], 64 v

    const int tid = threadIdx.x;
    const int b   = blockIdx.y;
    const int q0  = (blockIdx.x >> 3) * 8;
    const int v0  = (blockIdx.x & 7) * 64;

    const int v2 = (tid & 31) * 2;          // 2 v
    const int q2 = (tid >> 5) * 2;          // 2 q
    const int ar  = tid >> 3;               // attn stage row (tid<64: 0..7)
    const int akq = (tid & 7) * 4;
    const int vr  = tid >> 4;               // values stage row 0..7 (+8p)
    const int vq  = (tid & 15) * 4;

    const float* pAt = attn + (size_t)(b * TQ_ + q0 + ar) * TK_ + akq;
    const float* pV0 = values + (size_t)(b * TK_ + vr     ) * NV_ + v0 + vq;
    const float* pV1 = values + (size_t)(b * TK_ + vr +  8) * NV_ + v0 + vq;
    const float* pV2 = values + (size_t)(b * TK_ + vr + 16) * NV_ + v0 + vq;
    const float* pV3 = values + (size_t)(b * TK_ + vr + 24) * NV_ + v0 + vq;

    float4 af = {0.f,0.f,0.f,0.f};
    if (tid < 64) af = *(const float4*)pAt;
    float4 vf0 = *(const float4*)pV0;
    float4 vf1 = *(const float4*)pV1;
    float4 vf2 = *(const float4*)pV2;
    float4 vf3 = *(const float4*)pV3;

    float acc[2][2] = {{0.f,0.f},{0.f,0.f}};

    for (int c = 0; c < 16; ++c) {
        __syncthreads();
        if (tid < 64) {
            at[akq+0][ar] = af.x; at[akq+1][ar] = af.y;
            at[akq+2][ar] = af.z; at[akq+3][ar] = af.w;
        }
        *(float4*)&vt[vr     ][vq] = vf0;
        *(float4*)&vt[vr +  8][vq] = vf1;
        *(float4*)&vt[vr + 16][vq] = vf2;
        *(float4*)&vt[vr + 24][vq] = vf3;
        __syncthreads();
        if (c + 1 < 16) {
            pAt += 32; pV0 += 32 * NV_; pV1 += 32 * NV_;
            pV2 += 32 * NV_; pV3 += 32 * NV_;
            if (tid < 64) af = *(const float4*)pAt;
            vf0 = *(const float4*)pV0; vf1 = *(const float4*)pV1;
            vf2 = *(const float4*)pV2; vf3 = *(const float4*)pV3;
        }
#pragma unroll 8
        for (int kk = 0; kk < 32; ++kk) {
            const float2 a = *(const float2*)&at[kk][q2];
            const float2 v = *(const float2*)&vt[kk][v2];
            acc[0][0] = fmaf(a.x, v.x, acc[0][0]);
            acc[0][1] = fmaf(a.x, v.y, acc[0][1]);
            acc[1][0] = fmaf(a.y, v.x, acc[1][0]);
            acc[1][1] = fmaf(a.y, v.y, acc[1][1]);
        }
    }
    float2 o0 = {acc[0][0], acc[0][1]};
    float2 o1 = {acc[1][0], acc[1][1]};
    *(float2*)&outc[(size_t)(b * TQ_ + q0 + q2 + 0) * NV_ + v0 + v2] = o0;
    *(float2*)&outc[(size_t)(b * TQ_ + q0 + q2 + 1) * NV_ + v0 + v2] = o1;
}

// -------------------------------------------------------------- launch ----
extern "C" void kernel_launch(void* const* d_in, const int* in_sizes, int n_in,
                              void* d_out, int out_size, void* d_ws, size_t ws_size,
                              hipStream_t stream) {
    const float* query  = (const float*)d_in[0];
    const float* keys   = (const float*)d_in[1];
    const float* values = (const float*)d_in[2];
    const float* Wq     = (const float*)d_in[3];
    const float* bq     = (const float*)d_in[4];
    const float* Wk     = (const float*)d_in[5];
    const float* bk     = (const float*)d_in[6];
    const float* Wo     = (const float*)d_in[7];
    const float* bo     = (const float*)d_in[8];

    float* out_ctx  = (float*)d_out;                 // B*TQ*NV
    float* out_attn = out_ctx + B_ * TQ_ * NV_;      // B*TQ*TK
    float* qp = (float*)d_ws;                        // NQR*H  (pre-scaled)
    float* kp = qp + (size_t)NQR * H_;               // B*TK*H (pre-scaled)

    proj_kernel<<<dim3(NROWS / 16 * 2), 128, 0, stream>>>(
        query, keys, Wq, bq, Wk, bk, qp, kp);
    scores_kernel<<<dim3(TQ_ / 2, B_), 256, 0, stream>>>(qp, kp, Wo, bo, out_attn);
    context_kernel<<<dim3(128, B_), 128, 0, stream>>>(out_attn, values, out_ctx);
}